// Round 1
// baseline (120.151 us; speedup 1.0000x reference)
//
#include <hip/hip_runtime.h>
#include <math.h>

#define HIDDEN 256

// Kernel 1: build segment boundary array starts[0..G] from sorted batch ids.
// starts[g] = first node index with batch[i] >= g; starts[G] = N.
__global__ __launch_bounds__(256) void seg_starts_kernel(
    const int* __restrict__ batch, int* __restrict__ starts, int N, int G) {
  int i = blockIdx.x * blockDim.x + threadIdx.x;
  if (i >= N) return;
  int b = batch[i];
  int prev = (i == 0) ? -1 : batch[i - 1];
  for (int g = prev + 1; g <= b; ++g) starts[g] = i;
  if (i == N - 1) {
    for (int g = b + 1; g <= G; ++g) starts[g] = N;
  }
}

// Kernel 2: one 64-lane wave per graph. Each lane owns 4 hidden channels.
// Single pass over h: online-softmax attention pool + weighted mean pool + max pool.
__global__ __launch_bounds__(256) void pool_kernel(
    const float* __restrict__ h, const float* __restrict__ node_mult,
    const float* __restrict__ pressure, const float* __restrict__ attn_weight,
    const float* __restrict__ attn_bias, const float* __restrict__ W_pressure,
    const int* __restrict__ starts, float* __restrict__ out, int G) {
  const int wave = threadIdx.x >> 6;
  const int lane = threadIdx.x & 63;
  const int g = blockIdx.x * 4 + wave;
  if (g >= G) return;

  const int start = starts[g];
  const int end = starts[g + 1];

  const float4 w4 = *reinterpret_cast<const float4*>(attn_weight + 4 * lane);
  const float bias = attn_bias[0];

  float4 attn  = make_float4(0.f, 0.f, 0.f, 0.f);
  float4 meanv = make_float4(0.f, 0.f, 0.f, 0.f);
  float4 maxv  = make_float4(-INFINITY, -INFINITY, -INFINITY, -INFINITY);
  float m = -INFINITY;   // running segment max of scores (wave-uniform)
  float denom = 0.f;     // running sum of exp(score - m)
  float tmult = 0.f;     // total multiplicity

  for (int i = start; i < end; ++i) {
    const float4 hv =
        *reinterpret_cast<const float4*>(h + (size_t)i * HIDDEN + 4 * lane);
    const float mult = node_mult[i];  // uniform across lanes -> broadcast

    // dot(h_i, attn_weight): per-lane partial then 64-lane butterfly reduce
    float p = hv.x * w4.x + hv.y * w4.y + hv.z * w4.z + hv.w * w4.w;
#pragma unroll
    for (int off = 32; off >= 1; off >>= 1) p += __shfl_xor(p, off, 64);

    const float score = p + bias + __logf(fmaxf(mult, 1.f));  // wave-uniform

    if (score > m) {  // uniform branch (score, m uniform)
      const float scale = __expf(m - score);  // m=-inf -> scale=0
      denom *= scale;
      attn.x *= scale; attn.y *= scale; attn.z *= scale; attn.w *= scale;
      m = score;
    }
    const float e = __expf(score - m);
    denom += e;
    attn.x += hv.x * e;  attn.y += hv.y * e;
    attn.z += hv.z * e;  attn.w += hv.w * e;

    meanv.x += hv.x * mult;  meanv.y += hv.y * mult;
    meanv.z += hv.z * mult;  meanv.w += hv.w * mult;

    maxv.x = fmaxf(maxv.x, hv.x);  maxv.y = fmaxf(maxv.y, hv.y);
    maxv.z = fmaxf(maxv.z, hv.z);  maxv.w = fmaxf(maxv.w, hv.w);

    tmult += mult;
  }

  const float inv_tm  = 1.f / fmaxf(tmult, 1e-8f);
  const float inv_den = (denom > 0.f) ? 1.f / denom : 0.f;  // empty seg -> 0
  const float p_norm  = pressure[g] * (1.f / 300.f);
  const float4 wp4 = *reinterpret_cast<const float4*>(W_pressure + 4 * lane);

  float4 res;
  res.x = 0.5f * (meanv.x * inv_tm + attn.x * inv_den) + p_norm * wp4.x;
  res.y = 0.5f * (meanv.y * inv_tm + attn.y * inv_den) + p_norm * wp4.y;
  res.z = 0.5f * (meanv.z * inv_tm + attn.z * inv_den) + p_norm * wp4.z;
  res.w = 0.5f * (meanv.w * inv_tm + attn.w * inv_den) + p_norm * wp4.w;

  float* outg = out + (size_t)g * (2 * HIDDEN);
  *reinterpret_cast<float4*>(outg + 4 * lane) = res;
  *reinterpret_cast<float4*>(outg + HIDDEN + 4 * lane) = maxv;
}

extern "C" void kernel_launch(void* const* d_in, const int* in_sizes, int n_in,
                              void* d_out, int out_size, void* d_ws, size_t ws_size,
                              hipStream_t stream) {
  const float* h           = (const float*)d_in[0];
  const float* node_mult   = (const float*)d_in[1];
  const float* pressure    = (const float*)d_in[2];
  const float* attn_weight = (const float*)d_in[3];
  const float* attn_bias   = (const float*)d_in[4];
  const float* W_pressure  = (const float*)d_in[5];
  const int*   batch       = (const int*)d_in[6];

  const int N = in_sizes[1];  // node_mult length = N_NODES
  const int G = in_sizes[2];  // pressure length = N_GRAPHS

  int* starts = (int*)d_ws;   // (G+1) ints
  float* out = (float*)d_out;

  seg_starts_kernel<<<(N + 255) / 256, 256, 0, stream>>>(batch, starts, N, G);
  pool_kernel<<<(G + 3) / 4, 256, 0, stream>>>(h, node_mult, pressure,
                                               attn_weight, attn_bias,
                                               W_pressure, starts, out, G);
}

// Round 3
// 103.720 us; speedup vs baseline: 1.1584x; 1.1584x over previous
//
#include <hip/hip_runtime.h>
#include <math.h>

#define HIDDEN 256
#define CHUNK 8

typedef float fx4 __attribute__((ext_vector_type(4)));

// Kernel 1: build segment boundary array starts[0..G] from sorted batch ids.
__global__ __launch_bounds__(256) void seg_starts_kernel(
    const int* __restrict__ batch, int* __restrict__ starts, int N, int G) {
  int i = blockIdx.x * blockDim.x + threadIdx.x;
  if (i >= N) return;
  int b = batch[i];
  int prev = (i == 0) ? -1 : batch[i - 1];
  for (int g = prev + 1; g <= b; ++g) starts[g] = i;
  if (i == N - 1) {
    for (int g = b + 1; g <= G; ++g) starts[g] = N;
  }
}

// Kernel 2: one 64-lane wave per graph, lane owns 4 hidden channels.
// 8-node chunks: batched nontemporal loads, 8 interleaved butterfly reduces,
// single deferred rescale per chunk.
__global__ __launch_bounds__(256) void pool_kernel(
    const float* __restrict__ h, const float* __restrict__ node_mult,
    const float* __restrict__ pressure, const float* __restrict__ attn_weight,
    const float* __restrict__ attn_bias, const float* __restrict__ W_pressure,
    const int* __restrict__ starts, float* __restrict__ out, int G) {
  const int wave = threadIdx.x >> 6;
  const int lane = threadIdx.x & 63;
  const int g = blockIdx.x * 4 + wave;
  if (g >= G) return;

  const int start = starts[g];
  const int end = starts[g + 1];

  const fx4 w4 = *reinterpret_cast<const fx4*>(attn_weight + 4 * lane);
  const float bias = attn_bias[0];

  fx4 attn  = (fx4)(0.f);
  fx4 meanv = (fx4)(0.f);
  fx4 maxv  = (fx4)(-INFINITY);
  float m = -INFINITY;
  float denom = 0.f;
  float tmult = 0.f;

  int i = start;
  for (; i + CHUNK <= end; i += CHUNK) {
    fx4 hv[CHUNK];
    float mult[CHUNK];
#pragma unroll
    for (int j = 0; j < CHUNK; ++j) {
      hv[j] = __builtin_nontemporal_load(
          reinterpret_cast<const fx4*>(h + (size_t)(i + j) * HIDDEN + 4 * lane));
      mult[j] = node_mult[i + j];
    }

    float p[CHUNK];
#pragma unroll
    for (int j = 0; j < CHUNK; ++j)
      p[j] = hv[j].x * w4.x + hv[j].y * w4.y + hv[j].z * w4.z + hv[j].w * w4.w;

    // 8 independent butterfly chains, interleaved for latency hiding
#pragma unroll
    for (int off = 32; off >= 1; off >>= 1) {
#pragma unroll
      for (int j = 0; j < CHUNK; ++j) p[j] += __shfl_xor(p[j], off, 64);
    }

    float s[CHUNK];
#pragma unroll
    for (int j = 0; j < CHUNK; ++j)
      s[j] = p[j] + bias + __logf(fmaxf(mult[j], 1.f));

    // chunk max (wave-uniform values -> uniform branch)
    float cmax = s[0];
#pragma unroll
    for (int j = 1; j < CHUNK; ++j) cmax = fmaxf(cmax, s[j]);

    if (cmax > m) {
      const float scale = __expf(m - cmax);  // m=-inf -> 0
      denom *= scale;
      attn *= scale;
      m = cmax;
    }

#pragma unroll
    for (int j = 0; j < CHUNK; ++j) {
      const float e = __expf(s[j] - m);
      denom += e;
      attn += hv[j] * e;
      meanv += hv[j] * mult[j];
      maxv.x = fmaxf(maxv.x, hv[j].x);  maxv.y = fmaxf(maxv.y, hv[j].y);
      maxv.z = fmaxf(maxv.z, hv[j].z);  maxv.w = fmaxf(maxv.w, hv[j].w);
      tmult += mult[j];
    }
  }

  // remainder (<= 7 nodes)
  for (; i < end; ++i) {
    const fx4 hv = __builtin_nontemporal_load(
        reinterpret_cast<const fx4*>(h + (size_t)i * HIDDEN + 4 * lane));
    const float mult = node_mult[i];

    float p = hv.x * w4.x + hv.y * w4.y + hv.z * w4.z + hv.w * w4.w;
#pragma unroll
    for (int off = 32; off >= 1; off >>= 1) p += __shfl_xor(p, off, 64);

    const float score = p + bias + __logf(fmaxf(mult, 1.f));

    if (score > m) {
      const float scale = __expf(m - score);
      denom *= scale;
      attn *= scale;
      m = score;
    }
    const float e = __expf(score - m);
    denom += e;
    attn += hv * e;
    meanv += hv * mult;
    maxv.x = fmaxf(maxv.x, hv.x);  maxv.y = fmaxf(maxv.y, hv.y);
    maxv.z = fmaxf(maxv.z, hv.z);  maxv.w = fmaxf(maxv.w, hv.w);
    tmult += mult;
  }

  const float inv_tm  = 1.f / fmaxf(tmult, 1e-8f);
  const float inv_den = (denom > 0.f) ? 1.f / denom : 0.f;
  const float p_norm  = pressure[g] * (1.f / 300.f);
  const fx4 wp4 = *reinterpret_cast<const fx4*>(W_pressure + 4 * lane);

  fx4 res = 0.5f * (meanv * inv_tm + attn * inv_den) + p_norm * wp4;

  float* outg = out + (size_t)g * (2 * HIDDEN);
  *reinterpret_cast<fx4*>(outg + 4 * lane) = res;
  *reinterpret_cast<fx4*>(outg + HIDDEN + 4 * lane) = maxv;
}

extern "C" void kernel_launch(void* const* d_in, const int* in_sizes, int n_in,
                              void* d_out, int out_size, void* d_ws, size_t ws_size,
                              hipStream_t stream) {
  const float* h           = (const float*)d_in[0];
  const float* node_mult   = (const float*)d_in[1];
  const float* pressure    = (const float*)d_in[2];
  const float* attn_weight = (const float*)d_in[3];
  const float* attn_bias   = (const float*)d_in[4];
  const float* W_pressure  = (const float*)d_in[5];
  const int*   batch       = (const int*)d_in[6];

  const int N = in_sizes[1];
  const int G = in_sizes[2];

  int* starts = (int*)d_ws;
  float* out = (float*)d_out;

  seg_starts_kernel<<<(N + 255) / 256, 256, 0, stream>>>(batch, starts, N, G);
  pool_kernel<<<(G + 3) / 4, 256, 0, stream>>>(h, node_mult, pressure,
                                               attn_weight, attn_bias,
                                               W_pressure, starts, out, G);
}